// Round 20
// baseline (249.123 us; speedup 1.0000x reference)
//
#include <hip/hip_runtime.h>
#include <stdint.h>

#define NB 64
#define NR 1152
#define NI 64
#define NC 32
#define NO 32

typedef __attribute__((ext_vector_type(8))) short bf16x8;
typedef __attribute__((ext_vector_type(4))) float f32x4;
typedef float float4v __attribute__((ext_vector_type(4)));

__device__ __forceinline__ uint16_t f2bf(float f) {
  uint32_t u = __float_as_uint(f);
  return (uint16_t)((u + 0x7FFFu + ((u >> 16) & 1u)) >> 16);
}
__device__ __forceinline__ float bf2f(uint16_t h) {
  return __uint_as_float(((uint32_t)h) << 16);
}

// ---------------------------------------------------------------------------
// T0: x[b,r,i] fp32 -> xbf_hi/xbf_lo [r][b][i] bf16 (9.44 MB each, ~8 us).
// ---------------------------------------------------------------------------
__global__ __launch_bounds__(256, 4)
void k_xcvt(const float* __restrict__ x, uint16_t* __restrict__ xh,
            uint16_t* __restrict__ xl) {
  const int r = blockIdx.x;
  const int t = threadIdx.x;
  const int b = t >> 2, i0 = (t & 3) * 16;
  const float* src = x + ((size_t)b * NR + r) * NI + i0;

  union { uint16_t us[16]; uint4 v[2]; } hb, lb;
#pragma unroll
  for (int k = 0; k < 4; ++k) {
    const float4v v = __builtin_nontemporal_load(
        reinterpret_cast<const float4v*>(src + 4 * k));
#pragma unroll
    for (int j = 0; j < 4; ++j) {
      const uint16_t h = f2bf(v[j]);
      hb.us[k * 4 + j] = h;
      lb.us[k * 4 + j] = f2bf(v[j] - bf2f(h));
    }
  }
  const size_t dst = ((size_t)r * NB + b) * NI + i0;
  *reinterpret_cast<uint4*>(xh + dst)     = hb.v[0];
  *reinterpret_cast<uint4*>(xh + dst + 8) = hb.v[1];
  *reinterpret_cast<uint4*>(xl + dst)     = lb.v[0];
  *reinterpret_cast<uint4*>(xl + dst + 8) = lb.v[1];
}

// ---------------------------------------------------------------------------
// K1 (MFMA, split-bf16, proven math): c-QUAD per block + DIRECT-GLOBAL x frags.
// grid (NC/4, NR); block 256 = 4 waves; wave = b-tile of 16.
// x A-frags: per-lane private contiguous 16B from xh/xl (L3-hot, no LDS,
// no swizzle, no barrier dependency). W: 4 tiles staged hi/lo in 32 KB LDS
// (same byte layout as proven round-18 form) -> 5 blocks/CU at (256,5).
// Blocks halve (9216), x L3 re-reads halve, 1 barrier per 64 KB of W+P HBM.
// ---------------------------------------------------------------------------
__global__ __launch_bounds__(256, 5)
void k_priors(const uint16_t* __restrict__ xh, const uint16_t* __restrict__ xl,
              const float* __restrict__ W, float* __restrict__ P) {
  __shared__ __align__(16) uint16_t whs[4][NO * NI];   // 16 KB
  __shared__ __align__(16) uint16_t wls[4][NO * NI];   // 16 KB

  const int tid  = threadIdx.x;
  const int lane = tid & 63;
  const int mt   = tid >> 6;     // wave = b-tile
  const int c0   = blockIdx.x * 4;
  const int r    = blockIdx.y;

  // ---- stage W for 4 c's (i-pair pack, proven byte layout) ----
  {
    const int i2 = tid >> 3, o0 = (tid & 7) * 4;
#pragma unroll
    for (int cc = 0; cc < 4; ++cc) {
      const float* wsrc = W + (((size_t)(c0 + cc) * NR + r) * NI + 2 * i2) * NO + o0;
      const float4v f0 = __builtin_nontemporal_load(
          reinterpret_cast<const float4v*>(wsrc));        // i = 2i2
      const float4v f1 = __builtin_nontemporal_load(
          reinterpret_cast<const float4v*>(wsrc + NO));   // i = 2i2+1
#pragma unroll
      for (int j = 0; j < 4; ++j) {
        const int o = o0 + j;
        const float fa = f0[j], fb = f1[j];
        const uint16_t ha = f2bf(fa), hbv = f2bf(fb);
        const uint16_t la = f2bf(fa - bf2f(ha)), lbv = f2bf(fb - bf2f(hbv));
        const int ad = (o * 128 + i2 * 4) ^ ((o & 7) << 4);
        *reinterpret_cast<uint32_t*>((char*)whs[cc] + ad) =
            (uint32_t)ha | ((uint32_t)hbv << 16);
        *reinterpret_cast<uint32_t*>((char*)wls[cc] + ad) =
            (uint32_t)la | ((uint32_t)lbv << 16);
      }
    }
  }

  // ---- x A-frags: direct per-lane 16B global loads (same bytes the old
  //      LDS path delivered: row brow, i = 8*lg (kseg0) / 32+8*lg (kseg1)) ----
  const int lm = lane & 15;
  const int lg = lane >> 4;
  const int brow = mt * 16 + lm;
  const uint16_t* xrow_h = xh + ((size_t)r * NB + brow) * NI;
  const uint16_t* xrow_l = xl + ((size_t)r * NB + brow) * NI;
  const bf16x8 ah0 = *reinterpret_cast<const bf16x8*>(xrow_h + 8 * lg);
  const bf16x8 ah1 = *reinterpret_cast<const bf16x8*>(xrow_h + 32 + 8 * lg);
  const bf16x8 al0 = *reinterpret_cast<const bf16x8*>(xrow_l + 8 * lg);
  const bf16x8 al1 = *reinterpret_cast<const bf16x8*>(xrow_l + 32 + 8 * lg);

  __syncthreads();

  // ---- compute: 4 c's x 12 MFMA per wave, shared A-frags ----
  const int or0 = lm, or1 = 16 + lm;
  const int b00 = (or0 * 128 + (8 * lg) * 2) ^ ((or0 & 7) << 4);
  const int b01 = (or0 * 128 + (32 + 8 * lg) * 2) ^ ((or0 & 7) << 4);
  const int b10 = (or1 * 128 + (8 * lg) * 2) ^ ((or1 & 7) << 4);
  const int b11 = (or1 * 128 + (32 + 8 * lg) * 2) ^ ((or1 & 7) << 4);

#define RD(arr, off) (*reinterpret_cast<const bf16x8*>((const char*)(arr) + (off)))
#define MFMA(A, B, C) __builtin_amdgcn_mfma_f32_16x16x32_bf16(A, B, C, 0, 0, 0)

#pragma unroll
  for (int cc = 0; cc < 4; ++cc) {
    const uint16_t* wh = whs[cc];
    const uint16_t* wl = wls[cc];
    f32x4 acc0 = {0.f, 0.f, 0.f, 0.f}, acc1 = acc0;
    bf16x8 b;
    b = RD(wh, b00); acc0 = MFMA(ah0, b, acc0);   // hi*hi kseg0
    b = RD(wh, b10); acc1 = MFMA(ah0, b, acc1);
    b = RD(wl, b00); acc0 = MFMA(ah0, b, acc0);   // hi*lo kseg0
    b = RD(wl, b10); acc1 = MFMA(ah0, b, acc1);
    b = RD(wh, b01); acc0 = MFMA(ah1, b, acc0);   // hi*hi kseg1
    b = RD(wh, b11); acc1 = MFMA(ah1, b, acc1);
    b = RD(wl, b01); acc0 = MFMA(ah1, b, acc0);   // hi*lo kseg1
    b = RD(wl, b11); acc1 = MFMA(ah1, b, acc1);
    b = RD(wh, b00); acc0 = MFMA(al0, b, acc0);   // lo*hi kseg0
    b = RD(wh, b10); acc1 = MFMA(al0, b, acc1);
    b = RD(wh, b01); acc0 = MFMA(al1, b, acc0);   // lo*hi kseg1
    b = RD(wh, b11); acc1 = MFMA(al1, b, acc1);

#pragma unroll
    for (int reg = 0; reg < 4; ++reg) {
      const int bb = mt * 16 + lg * 4 + reg;
      float* dst = P + (((size_t)(c0 + cc) * NB + bb) * NR + r) * NO;
      __builtin_nontemporal_store(acc0[reg], dst + lm);
      __builtin_nontemporal_store(acc1[reg], dst + 16 + lm);
    }
  }
#undef RD
#undef MFMA
}

// ---------------------------------------------------------------------------
// K2: routing — 512-thread blocks, byte-exact round-19 proven form.
// ---------------------------------------------------------------------------
__device__ __forceinline__ void merge4(float& m, float& Z, float4& T,
                                       float m2, float Z2, const float4& T2) {
  const float mn = fmaxf(m, m2);
  const float a1 = __expf(m - mn), a2 = __expf(m2 - mn);
  Z   = Z * a1 + Z2 * a2;
  T.x = T.x * a1 + T2.x * a2;
  T.y = T.y * a1 + T2.y * a2;
  T.z = T.z * a1 + T2.z * a2;
  T.w = T.w * a1 + T2.w * a2;
  m = mn;
}

__global__ __launch_bounds__(512, 1)
void k_route(const float* __restrict__ P, float* __restrict__ out) {
  __shared__ float red_s[8][8][8];   // [wave][slice][m,Z,T0..3,pad2]
  __shared__ float u_s[NO];

  const int tid  = threadIdx.x;
  const int lane = tid & 63;
  const int wave = tid >> 6;
  const int sl   = tid & 7;   // o-slice: o = sl*4 + 0..3
  const int grp  = tid >> 3;  // row group 0..63; rows r = grp + 64*j
  const int b    = blockIdx.x;
  const int c    = blockIdx.y;
  const float* Pb = P + ((size_t)c * NB + b) * ((size_t)NR * NO);

  float4 p[18];
#pragma unroll
  for (int j = 0; j < 18; ++j) {
    const float4v t = __builtin_nontemporal_load(
        reinterpret_cast<const float4v*>(Pb + (size_t)(grp + 64 * j) * NO + sl * 4));
    p[j].x = t.x; p[j].y = t.y; p[j].z = t.z; p[j].w = t.w;
  }

  // ---- iteration 0: uniform softmax -> S0 = mean_r p ----
  {
    float4 T = p[0];
#pragma unroll
    for (int j = 1; j < 18; ++j) {
      T.x += p[j].x; T.y += p[j].y; T.z += p[j].z; T.w += p[j].w;
    }
#pragma unroll
    for (int off = 8; off <= 32; off <<= 1) {
      T.x += __shfl_xor(T.x, off); T.y += __shfl_xor(T.y, off);
      T.z += __shfl_xor(T.z, off); T.w += __shfl_xor(T.w, off);
    }
    if (lane < 8) {
      red_s[wave][sl][2] = T.x; red_s[wave][sl][3] = T.y;
      red_s[wave][sl][4] = T.z; red_s[wave][sl][5] = T.w;
    }
  }
  __syncthreads();
  if (tid < 8) {
    float4 S = make_float4(0.f, 0.f, 0.f, 0.f);
#pragma unroll
    for (int ww = 0; ww < 8; ++ww) {
      S.x += red_s[ww][tid][2]; S.y += red_s[ww][tid][3];
      S.z += red_s[ww][tid][4]; S.w += red_s[ww][tid][5];
    }
    S.x *= (1.f / NR); S.y *= (1.f / NR); S.z *= (1.f / NR); S.w *= (1.f / NR);
    float n2 = S.x * S.x + S.y * S.y + S.z * S.z + S.w * S.w;
    n2 += __shfl_xor(n2, 1); n2 += __shfl_xor(n2, 2); n2 += __shfl_xor(n2, 4);
    const float scale = n2 / ((1.f + n2) * sqrtf(n2));
    u_s[tid * 4 + 0] = S.x * scale; u_s[tid * 4 + 1] = S.y * scale;
    u_s[tid * 4 + 2] = S.z * scale; u_s[tid * 4 + 3] = S.w * scale;
  }
  __syncthreads();

  float4 u = *reinterpret_cast<const float4*>(&u_s[sl * 4]);
  float l1[18];

  for (int it = 1; it <= 2; ++it) {
    float m = -3.0e38f, Z = 0.f;
    float4 T = make_float4(0.f, 0.f, 0.f, 0.f);
#pragma unroll
    for (int j = 0; j < 18; ++j) {
      float d = p[j].x * u.x + p[j].y * u.y + p[j].z * u.z + p[j].w * u.w;
      d += __shfl_xor(d, 1); d += __shfl_xor(d, 2); d += __shfl_xor(d, 4);
      float l;
      if (it == 1) { l1[j] = d; l = d; }
      else         { l = l1[j] + d; }
      const float mn = fmaxf(m, l);
      const float a = __expf(m - mn);
      const float e = __expf(l - mn);
      Z   = Z * a + e;
      T.x = T.x * a + e * p[j].x; T.y = T.y * a + e * p[j].y;
      T.z = T.z * a + e * p[j].z; T.w = T.w * a + e * p[j].w;
      m = mn;
    }
#pragma unroll
    for (int off = 8; off <= 32; off <<= 1) {
      const float m2 = __shfl_xor(m, off);
      const float Z2 = __shfl_xor(Z, off);
      float4 T2;
      T2.x = __shfl_xor(T.x, off); T2.y = __shfl_xor(T.y, off);
      T2.z = __shfl_xor(T.z, off); T2.w = __shfl_xor(T.w, off);
      merge4(m, Z, T, m2, Z2, T2);
    }
    if (lane < 8) {
      red_s[wave][sl][0] = m;   red_s[wave][sl][1] = Z;
      red_s[wave][sl][2] = T.x; red_s[wave][sl][3] = T.y;
      red_s[wave][sl][4] = T.z; red_s[wave][sl][5] = T.w;
    }
    __syncthreads();
    if (tid < 8) {
      float mm = red_s[0][tid][0], ZZ = red_s[0][tid][1];
      float4 TT = make_float4(red_s[0][tid][2], red_s[0][tid][3],
                              red_s[0][tid][4], red_s[0][tid][5]);
#pragma unroll
      for (int ww = 1; ww < 8; ++ww) {
        const float4 T2 = make_float4(red_s[ww][tid][2], red_s[ww][tid][3],
                                      red_s[ww][tid][4], red_s[ww][tid][5]);
        merge4(mm, ZZ, TT, red_s[ww][tid][0], red_s[ww][tid][1], T2);
      }
      const float inv = 1.f / ZZ;
      float4 S = make_float4(TT.x * inv, TT.y * inv, TT.z * inv, TT.w * inv);
      float n2 = S.x * S.x + S.y * S.y + S.z * S.z + S.w * S.w;
      n2 += __shfl_xor(n2, 1); n2 += __shfl_xor(n2, 2); n2 += __shfl_xor(n2, 4);
      const float scale = n2 / ((1.f + n2) * sqrtf(n2));
      if (it == 1) {
        u_s[tid * 4 + 0] = S.x * scale; u_s[tid * 4 + 1] = S.y * scale;
        u_s[tid * 4 + 2] = S.z * scale; u_s[tid * 4 + 3] = S.w * scale;
      } else {
        *reinterpret_cast<float4*>(out + ((size_t)b * NC + c) * NO + tid * 4) =
            make_float4(S.x * scale, S.y * scale, S.z * scale, S.w * scale);
      }
    }
    __syncthreads();
    if (it == 1) u = *reinterpret_cast<const float4*>(&u_s[sl * 4]);
  }
}

extern "C" void kernel_launch(void* const* d_in, const int* in_sizes, int n_in,
                              void* d_out, int out_size, void* d_ws, size_t ws_size,
                              hipStream_t stream) {
  const float* x = (const float*)d_in[0];
  // d_in[1] (cond) is unused by the reference computation
  const float* W = (const float*)d_in[2];
  float* out = (float*)d_out;

  uint16_t* xh = (uint16_t*)d_ws;                     // 9.44 MB
  const size_t xbf_elems = (size_t)NR * NB * NI;
  uint16_t* xl = xh + xbf_elems;                      // 9.44 MB
  float* P = (float*)(xl + xbf_elems);                // 302 MB

  k_xcvt<<<NR, 256, 0, stream>>>(x, xh, xl);
  k_priors<<<dim3(NC / 4, NR), 256, 0, stream>>>(xh, xl, W, P);
  k_route<<<dim3(NB, NC), 512, 0, stream>>>(P, out);
}

// Round 21
// 242.612 us; speedup vs baseline: 1.0268x; 1.0268x over previous
//
#include <hip/hip_runtime.h>
#include <stdint.h>

#define NB 64
#define NR 1152
#define NI 64
#define NC 32
#define NO 32

typedef __attribute__((ext_vector_type(8))) short bf16x8;
typedef __attribute__((ext_vector_type(4))) float f32x4;
typedef float float4v __attribute__((ext_vector_type(4)));

__device__ __forceinline__ uint16_t f2bf(float f) {
  uint32_t u = __float_as_uint(f);
  return (uint16_t)((u + 0x7FFFu + ((u >> 16) & 1u)) >> 16);
}
__device__ __forceinline__ float bf2f(uint16_t h) {
  return __uint_as_float(((uint32_t)h) << 16);
}

// ---------------------------------------------------------------------------
// T0: x[b,r,i] fp32 -> xbf_hi/xbf_lo [r][b][i] bf16 (9.44 MB each, ~8 us).
// (byte-exact round-19 proven form)
// ---------------------------------------------------------------------------
__global__ __launch_bounds__(256, 4)
void k_xcvt(const float* __restrict__ x, uint16_t* __restrict__ xh,
            uint16_t* __restrict__ xl) {
  const int r = blockIdx.x;
  const int t = threadIdx.x;
  const int b = t >> 2, i0 = (t & 3) * 16;
  const float* src = x + ((size_t)b * NR + r) * NI + i0;

  union { uint16_t us[16]; uint4 v[2]; } hb, lb;
#pragma unroll
  for (int k = 0; k < 4; ++k) {
    const float4v v = __builtin_nontemporal_load(
        reinterpret_cast<const float4v*>(src + 4 * k));
#pragma unroll
    for (int j = 0; j < 4; ++j) {
      const uint16_t h = f2bf(v[j]);
      hb.us[k * 4 + j] = h;
      lb.us[k * 4 + j] = f2bf(v[j] - bf2f(h));
    }
  }
  const size_t dst = ((size_t)r * NB + b) * NI + i0;
  *reinterpret_cast<uint4*>(xh + dst)     = hb.v[0];
  *reinterpret_cast<uint4*>(xh + dst + 8) = hb.v[1];
  *reinterpret_cast<uint4*>(xl + dst)     = lb.v[0];
  *reinterpret_cast<uint4*>(xl + dst + 8) = lb.v[1];
}

// ---------------------------------------------------------------------------
// K1 (MFMA, split-bf16, c-PAIR per block) — byte-exact round-19 proven form
// (REVERTED from round-20's c-quad/global-x experiment which regressed 2%).
// ---------------------------------------------------------------------------
__global__ __launch_bounds__(256, 5)
void k_priors(const uint16_t* __restrict__ xh, const uint16_t* __restrict__ xl,
              const float* __restrict__ W, float* __restrict__ P) {
  __shared__ __align__(16) uint16_t xhs[NB * NI];      // 8 KB
  __shared__ __align__(16) uint16_t xls[NB * NI];      // 8 KB
  __shared__ __align__(16) uint16_t whs[2][NO * NI];   // 8 KB
  __shared__ __align__(16) uint16_t wls[2][NO * NI];   // 8 KB

  const int tid  = threadIdx.x;
  const int lane = tid & 63;
  const int mt   = tid >> 6;     // wave = b-tile
  const int c0   = blockIdx.x * 2;
  const int r    = blockIdx.y;

  // ---- stage x hi/lo ----
  {
    const int b = tid >> 2, i0 = (tid & 3) * 16;
    const size_t src = ((size_t)r * NB + b) * NI + i0;
    const int sw = (b & 7) << 4;
    const int a0 = (b * 128 + i0 * 2) ^ sw;
    const int a1 = (b * 128 + (i0 + 8) * 2) ^ sw;
    uint4 v;
    v = *reinterpret_cast<const uint4*>(xh + src);
    *reinterpret_cast<uint4*>((char*)xhs + a0) = v;
    v = *reinterpret_cast<const uint4*>(xh + src + 8);
    *reinterpret_cast<uint4*>((char*)xhs + a1) = v;
    v = *reinterpret_cast<const uint4*>(xl + src);
    *reinterpret_cast<uint4*>((char*)xls + a0) = v;
    v = *reinterpret_cast<const uint4*>(xl + src + 8);
    *reinterpret_cast<uint4*>((char*)xls + a1) = v;
  }
  // ---- stage W for both c's ----
  {
    const int i2 = tid >> 3, o0 = (tid & 7) * 4;
#pragma unroll
    for (int cc = 0; cc < 2; ++cc) {
      const float* wsrc = W + (((size_t)(c0 + cc) * NR + r) * NI + 2 * i2) * NO + o0;
      const float4v f0 = __builtin_nontemporal_load(
          reinterpret_cast<const float4v*>(wsrc));        // i = 2i2
      const float4v f1 = __builtin_nontemporal_load(
          reinterpret_cast<const float4v*>(wsrc + NO));   // i = 2i2+1
#pragma unroll
      for (int j = 0; j < 4; ++j) {
        const int o = o0 + j;
        const float fa = f0[j], fb = f1[j];
        const uint16_t ha = f2bf(fa), hbv = f2bf(fb);
        const uint16_t la = f2bf(fa - bf2f(ha)), lbv = f2bf(fb - bf2f(hbv));
        const int ad = (o * 128 + i2 * 4) ^ ((o & 7) << 4);
        *reinterpret_cast<uint32_t*>((char*)whs[cc] + ad) =
            (uint32_t)ha | ((uint32_t)hbv << 16);
        *reinterpret_cast<uint32_t*>((char*)wls[cc] + ad) =
            (uint32_t)la | ((uint32_t)lbv << 16);
      }
    }
  }
  __syncthreads();

  // ---- compute: 24 MFMA per wave (12 per c), shared A-frags ----
  const int lm = lane & 15;
  const int lg = lane >> 4;
  const int brow = mt * 16 + lm;
  const int aswz = (brow & 7) << 4;
  const int a0 = (brow * 128 + (8 * lg) * 2) ^ aswz;        // kseg 0
  const int a1 = (brow * 128 + (32 + 8 * lg) * 2) ^ aswz;   // kseg 1
  const int or0 = lm, or1 = 16 + lm;
  const int b00 = (or0 * 128 + (8 * lg) * 2) ^ ((or0 & 7) << 4);
  const int b01 = (or0 * 128 + (32 + 8 * lg) * 2) ^ ((or0 & 7) << 4);
  const int b10 = (or1 * 128 + (8 * lg) * 2) ^ ((or1 & 7) << 4);
  const int b11 = (or1 * 128 + (32 + 8 * lg) * 2) ^ ((or1 & 7) << 4);

#define RD(arr, off) (*reinterpret_cast<const bf16x8*>((const char*)(arr) + (off)))
#define MFMA(A, B, C) __builtin_amdgcn_mfma_f32_16x16x32_bf16(A, B, C, 0, 0, 0)

  const bf16x8 ah0 = RD(xhs, a0);
  const bf16x8 ah1 = RD(xhs, a1);
  const bf16x8 al0 = RD(xls, a0);
  const bf16x8 al1 = RD(xls, a1);

#pragma unroll
  for (int cc = 0; cc < 2; ++cc) {
    const uint16_t* wh = whs[cc];
    const uint16_t* wl = wls[cc];
    f32x4 acc0 = {0.f, 0.f, 0.f, 0.f}, acc1 = acc0;
    bf16x8 b;
    b = RD(wh, b00); acc0 = MFMA(ah0, b, acc0);   // hi*hi kseg0
    b = RD(wh, b10); acc1 = MFMA(ah0, b, acc1);
    b = RD(wl, b00); acc0 = MFMA(ah0, b, acc0);   // hi*lo kseg0
    b = RD(wl, b10); acc1 = MFMA(ah0, b, acc1);
    b = RD(wh, b01); acc0 = MFMA(ah1, b, acc0);   // hi*hi kseg1
    b = RD(wh, b11); acc1 = MFMA(ah1, b, acc1);
    b = RD(wl, b01); acc0 = MFMA(ah1, b, acc0);   // hi*lo kseg1
    b = RD(wl, b11); acc1 = MFMA(ah1, b, acc1);
    b = RD(wh, b00); acc0 = MFMA(al0, b, acc0);   // lo*hi kseg0
    b = RD(wh, b10); acc1 = MFMA(al0, b, acc1);
    b = RD(wh, b01); acc0 = MFMA(al1, b, acc0);   // lo*hi kseg1
    b = RD(wh, b11); acc1 = MFMA(al1, b, acc1);

#pragma unroll
    for (int reg = 0; reg < 4; ++reg) {
      const int bb = mt * 16 + lg * 4 + reg;
      float* dst = P + (((size_t)(c0 + cc) * NB + bb) * NR + r) * NO;
      __builtin_nontemporal_store(acc0[reg], dst + lm);
      __builtin_nontemporal_store(acc1[reg], dst + 16 + lm);
    }
  }
#undef RD
#undef MFMA
}

// ---------------------------------------------------------------------------
// K2: routing — 512 threads. ONLY delta vs round 19: launch_bounds (512,2)
// caps VGPR at 128 and GUARANTEES 2 blocks/CU (live set ~118 VGPR).
// Block B's 147KB load burst overlaps block A's 3-iteration compute.
// ---------------------------------------------------------------------------
__device__ __forceinline__ void merge4(float& m, float& Z, float4& T,
                                       float m2, float Z2, const float4& T2) {
  const float mn = fmaxf(m, m2);
  const float a1 = __expf(m - mn), a2 = __expf(m2 - mn);
  Z   = Z * a1 + Z2 * a2;
  T.x = T.x * a1 + T2.x * a2;
  T.y = T.y * a1 + T2.y * a2;
  T.z = T.z * a1 + T2.z * a2;
  T.w = T.w * a1 + T2.w * a2;
  m = mn;
}

__global__ __launch_bounds__(512, 2)
void k_route(const float* __restrict__ P, float* __restrict__ out) {
  __shared__ float red_s[8][8][8];   // [wave][slice][m,Z,T0..3,pad2]
  __shared__ float u_s[NO];

  const int tid  = threadIdx.x;
  const int lane = tid & 63;
  const int wave = tid >> 6;
  const int sl   = tid & 7;   // o-slice: o = sl*4 + 0..3
  const int grp  = tid >> 3;  // row group 0..63; rows r = grp + 64*j
  const int b    = blockIdx.x;
  const int c    = blockIdx.y;
  const float* Pb = P + ((size_t)c * NB + b) * ((size_t)NR * NO);

  float4 p[18];
#pragma unroll
  for (int j = 0; j < 18; ++j) {
    const float4v t = __builtin_nontemporal_load(
        reinterpret_cast<const float4v*>(Pb + (size_t)(grp + 64 * j) * NO + sl * 4));
    p[j].x = t.x; p[j].y = t.y; p[j].z = t.z; p[j].w = t.w;
  }

  // ---- iteration 0: uniform softmax -> S0 = mean_r p ----
  {
    float4 T = p[0];
#pragma unroll
    for (int j = 1; j < 18; ++j) {
      T.x += p[j].x; T.y += p[j].y; T.z += p[j].z; T.w += p[j].w;
    }
#pragma unroll
    for (int off = 8; off <= 32; off <<= 1) {
      T.x += __shfl_xor(T.x, off); T.y += __shfl_xor(T.y, off);
      T.z += __shfl_xor(T.z, off); T.w += __shfl_xor(T.w, off);
    }
    if (lane < 8) {
      red_s[wave][sl][2] = T.x; red_s[wave][sl][3] = T.y;
      red_s[wave][sl][4] = T.z; red_s[wave][sl][5] = T.w;
    }
  }
  __syncthreads();
  if (tid < 8) {
    float4 S = make_float4(0.f, 0.f, 0.f, 0.f);
#pragma unroll
    for (int ww = 0; ww < 8; ++ww) {
      S.x += red_s[ww][tid][2]; S.y += red_s[ww][tid][3];
      S.z += red_s[ww][tid][4]; S.w += red_s[ww][tid][5];
    }
    S.x *= (1.f / NR); S.y *= (1.f / NR); S.z *= (1.f / NR); S.w *= (1.f / NR);
    float n2 = S.x * S.x + S.y * S.y + S.z * S.z + S.w * S.w;
    n2 += __shfl_xor(n2, 1); n2 += __shfl_xor(n2, 2); n2 += __shfl_xor(n2, 4);
    const float scale = n2 / ((1.f + n2) * sqrtf(n2));
    u_s[tid * 4 + 0] = S.x * scale; u_s[tid * 4 + 1] = S.y * scale;
    u_s[tid * 4 + 2] = S.z * scale; u_s[tid * 4 + 3] = S.w * scale;
  }
  __syncthreads();

  float4 u = *reinterpret_cast<const float4*>(&u_s[sl * 4]);
  float l1[18];

  for (int it = 1; it <= 2; ++it) {
    float m = -3.0e38f, Z = 0.f;
    float4 T = make_float4(0.f, 0.f, 0.f, 0.f);
#pragma unroll
    for (int j = 0; j < 18; ++j) {
      float d = p[j].x * u.x + p[j].y * u.y + p[j].z * u.z + p[j].w * u.w;
      d += __shfl_xor(d, 1); d += __shfl_xor(d, 2); d += __shfl_xor(d, 4);
      float l;
      if (it == 1) { l1[j] = d; l = d; }
      else         { l = l1[j] + d; }
      const float mn = fmaxf(m, l);
      const float a = __expf(m - mn);
      const float e = __expf(l - mn);
      Z   = Z * a + e;
      T.x = T.x * a + e * p[j].x; T.y = T.y * a + e * p[j].y;
      T.z = T.z * a + e * p[j].z; T.w = T.w * a + e * p[j].w;
      m = mn;
    }
#pragma unroll
    for (int off = 8; off <= 32; off <<= 1) {
      const float m2 = __shfl_xor(m, off);
      const float Z2 = __shfl_xor(Z, off);
      float4 T2;
      T2.x = __shfl_xor(T.x, off); T2.y = __shfl_xor(T.y, off);
      T2.z = __shfl_xor(T.z, off); T2.w = __shfl_xor(T.w, off);
      merge4(m, Z, T, m2, Z2, T2);
    }
    if (lane < 8) {
      red_s[wave][sl][0] = m;   red_s[wave][sl][1] = Z;
      red_s[wave][sl][2] = T.x; red_s[wave][sl][3] = T.y;
      red_s[wave][sl][4] = T.z; red_s[wave][sl][5] = T.w;
    }
    __syncthreads();
    if (tid < 8) {
      float mm = red_s[0][tid][0], ZZ = red_s[0][tid][1];
      float4 TT = make_float4(red_s[0][tid][2], red_s[0][tid][3],
                              red_s[0][tid][4], red_s[0][tid][5]);
#pragma unroll
      for (int ww = 1; ww < 8; ++ww) {
        const float4 T2 = make_float4(red_s[ww][tid][2], red_s[ww][tid][3],
                                      red_s[ww][tid][4], red_s[ww][tid][5]);
        merge4(mm, ZZ, TT, red_s[ww][tid][0], red_s[ww][tid][1], T2);
      }
      const float inv = 1.f / ZZ;
      float4 S = make_float4(TT.x * inv, TT.y * inv, TT.z * inv, TT.w * inv);
      float n2 = S.x * S.x + S.y * S.y + S.z * S.z + S.w * S.w;
      n2 += __shfl_xor(n2, 1); n2 += __shfl_xor(n2, 2); n2 += __shfl_xor(n2, 4);
      const float scale = n2 / ((1.f + n2) * sqrtf(n2));
      if (it == 1) {
        u_s[tid * 4 + 0] = S.x * scale; u_s[tid * 4 + 1] = S.y * scale;
        u_s[tid * 4 + 2] = S.z * scale; u_s[tid * 4 + 3] = S.w * scale;
      } else {
        *reinterpret_cast<float4*>(out + ((size_t)b * NC + c) * NO + tid * 4) =
            make_float4(S.x * scale, S.y * scale, S.z * scale, S.w * scale);
      }
    }
    __syncthreads();
    if (it == 1) u = *reinterpret_cast<const float4*>(&u_s[sl * 4]);
  }
}

extern "C" void kernel_launch(void* const* d_in, const int* in_sizes, int n_in,
                              void* d_out, int out_size, void* d_ws, size_t ws_size,
                              hipStream_t stream) {
  const float* x = (const float*)d_in[0];
  // d_in[1] (cond) is unused by the reference computation
  const float* W = (const float*)d_in[2];
  float* out = (float*)d_out;

  uint16_t* xh = (uint16_t*)d_ws;                     // 9.44 MB
  const size_t xbf_elems = (size_t)NR * NB * NI;
  uint16_t* xl = xh + xbf_elems;                      // 9.44 MB
  float* P = (float*)(xl + xbf_elems);                // 302 MB

  k_xcvt<<<NR, 256, 0, stream>>>(x, xh, xl);
  k_priors<<<dim3(NC / 2, NR), 256, 0, stream>>>(xh, xl, W, P);
  k_route<<<dim3(NB, NC), 512, 0, stream>>>(P, out);
}